// Round 5
// baseline (126.737 us; speedup 1.0000x reference)
//
#include <hip/hip_runtime.h>

namespace {

constexpr int LMAX = 10;
constexpr double PI_D = 3.14159265358979323846;

constexpr double dfact(int n) {
    double r = 1.0;
    for (int i = 2; i <= n; ++i) r *= (double)i;
    return r;
}

constexpr double csqrt(double x) {
    if (x <= 0.0) return 0.0;
    double g = x > 1.0 ? x : 1.0;
    for (int i = 0; i < 100; ++i) g = 0.5 * (g + x / g);
    return g;
}

constexpr double FACT[LMAX + 1] = {1., 1., 2., 6., 24., 120., 720., 5040., 40320., 362880., 3628800.};

// ---- accumulator slot layout (single part, all l) -------------------------
// For each l: (l+1) real slots (m=0..l) then l imag slots (m=1..l), based at l^2.
constexpr int slot_r(int l, int m) { return l * l + m; }
constexpr int slot_i(int l, int m) { return l * l + (l + 1) + (m - 1); }
constexpr int NA = (LMAX + 1) * (LMAX + 1);  // 121

// Horner coefficient for the collapsed imag sum: (-1)^q / ((q+m)! q! (l-m-2q)!)
constexpr float ci_coef(int l, int m, int q) {
    const double c = 1.0 / (FACT[q + m] * FACT[q] * FACT[l - m - 2 * q]);
    return (q & 1) ? (float)(-c) : (float)c;
}

struct Tables {
    int   map[NA];
    float scl[NA];
};

constexpr Tables make_tables() {
    Tables t{};
    for (int l = 0; l <= LMAX; ++l) {
        for (int m = 0; m <= l; ++m) {
            const int k = slot_r(l, m);
            const double scale =
                csqrt(dfact(l + m) * dfact(l - m)) * csqrt((2 * l + 1) / (4.0 * PI_D));
            // T==1 pairs (m >= l-1, m>=1): inner coefficient folded into scl.
            const double fold = (m >= 1 && (l - m) <= 1) ? 1.0 / (dfact(m) * dfact(l - m)) : 1.0;
            if (m == 0) {
                t.map[k] = l * l + l;
                t.scl[k] = (float)(scale * fold);
            } else {
                const double f = csqrt(2.0) * ((m & 1) ? -1.0 : 1.0);
                t.map[k] = l * l + l + m;
                t.scl[k] = (float)(f * scale * fold);
            }
        }
        for (int m = 1; m <= l; ++m) {
            const int k = slot_i(l, m);
            const double scale =
                csqrt(dfact(l + m) * dfact(l - m)) * csqrt((2 * l + 1) / (4.0 * PI_D));
            const double f    = csqrt(2.0) * ((m & 1) ? -1.0 : 1.0);
            const double fold = ((l - m) <= 1) ? 1.0 / (dfact(m) * dfact(l - m)) : 1.0;
            t.map[k] = l * l + l - m;
            t.scl[k] = (float)(f * scale * fold);
        }
    }
    return t;
}

__constant__ Tables c_tab = make_tables();

}  // namespace

// Algebra (exact in fp up to reassociation):
//   z1 = (-x/2, -y/2), z2 = -conj(z1)  =>  one power table.
//   real term:  Re(z1^p)^2 - Im(z1^q)^2 = sr[p] - si[q]
//   imag p-sum collapses to  zi[m] * Horner_q(+-c * rho^q),  rho = |z1|^2.
//   T==1 (m >= l-1) pairs: coefficient folded into host-side scl.
//
// SINGLE part (was 2): rounds 2-4 pinned time at ~62-63 us across 1-pt/2-pt
// unroll, 84-116 VGPR, and 3-6 blocks/CU — issue count and residency tweaks
// both exhausted.  The remaining structural duplication was the 2-part split:
// every point scanned twice, preamble (~250 instr) executed twice.  Registers
// are not the wall (116 used, no spill), so the 121-accumulator monolith under
// a 256-VGPR cap halves total issue.  Spill canary: WRITE_SIZE (now 228 KB)
// jumping to MB-scale means the acc array spilled -> revert to 2 parts.
__global__ __launch_bounds__(256, 2) void sht_kernel(const float* __restrict__ pos,
                                                     float* __restrict__ out, int n, int nblk) {
    constexpr int PL = LMAX;
    constexpr int QX = PL / 2;  // max si index used: q <= (l-m)/2 <= 5

    float acc[NA];
#pragma unroll
    for (int k = 0; k < NA; ++k) acc[k] = 0.f;

    const int tid    = (int)blockIdx.x * 256 + (int)threadIdx.x;
    const int stride = nblk * 256;

    int   i = tid;
    float x = 0.f, y = 0.f, z0 = 0.f;
    if (i < n) {
        x  = pos[3 * i + 0];
        y  = pos[3 * i + 1];
        z0 = pos[3 * i + 2];
    }

    while (i < n) {
        // software-pipelined prefetch of the next point
        const int inext = i + stride;
        float     px = 0.f, py = 0.f, pz = 0.f;
        if (inext < n) {
            px = pos[3 * inext + 0];
            py = pos[3 * inext + 1];
            pz = pos[3 * inext + 2];
        }

        const float r2  = x * x + y * y + z0 * z0;
        const float nrm = sqrtf(r2);
        const float w0  = (nrm > 0.f) ? z0 : 0.f;  // x0 * mask

        const float ar  = -0.5f * x, ai = -0.5f * y;
        const float rho = ar * ar + ai * ai;  // |z1|^2 = (x^2+y^2)/4

        // Power tables: zi[] full, sr[p]=Re(z1^p)^2 full, si[p]=Im^2 to QX.
        // Re(z1^p) is a rolling scalar.
        float zi[PL + 1], sr[PL + 1], si[QX + 1];
        zi[0] = 0.f;
        sr[0] = 1.f;
        si[0] = 0.f;
        float zrc = 1.f;
#pragma unroll
        for (int p = 1; p <= PL; ++p) {
            const float nzr = ar * zrc - ai * zi[p - 1];
            zi[p]           = ar * zi[p - 1] + ai * zrc;
            zrc             = nzr;
            sr[p]           = zrc * zrc;
            if (p <= QX) si[p] = zi[p] * zi[p];  // condition folded at unroll
        }
        float rp[PL + 1];
        rp[0] = 1.f;
#pragma unroll
        for (int l = 1; l <= PL; ++l) rp[l] = rp[l - 1] * nrm;

#pragma unroll
        for (int l = 0; l <= LMAX; ++l) {
            const float wrl = w0 * rp[l];
#pragma unroll
            for (int m = 0; m <= l; ++m) {
                const int Q = (l - m) >> 1;  // highest q in the sums
                if (m >= 1 && Q == 0) {
                    // single-term pair: coefficient folded into c_tab.scl
                    acc[slot_r(l, m)] += sr[m] * wrl;
                    acc[slot_i(l, m)] += zi[m] * wrl;
                } else {
                    float shr = 0.f;
#pragma unroll
                    for (int p = m; 2 * p <= l + m; ++p) {
                        const int   q  = p - m;
                        const float cr = (float)(1.0 / (FACT[p] * FACT[q] * FACT[l - 2 * p + m]));
                        shr += (sr[p] - si[q]) * cr;
                    }
                    acc[slot_r(l, m)] += shr * wrl;
                    if (m >= 1) {
                        // shi = zi[m] * sum_q (+-c) rho^q   (Horner in rho)
                        float t = ci_coef(l, m, Q);
#pragma unroll
                        for (int q = Q - 1; q >= 0; --q) t = t * rho + ci_coef(l, m, q);
                        acc[slot_i(l, m)] += (t * zi[m]) * wrl;
                    }
                }
            }
        }

        i  = inext;
        x  = px;
        y  = py;
        z0 = pz;
    }

    // Wave (64-lane) shuffle reduction, then cross-wave via LDS.
    __shared__ float red[4][NA];
    const int lane = threadIdx.x & 63;
    const int wav  = threadIdx.x >> 6;
#pragma unroll
    for (int k = 0; k < NA; ++k) {
        float v = acc[k];
#pragma unroll
        for (int off = 32; off > 0; off >>= 1) v += __shfl_down(v, off, 64);
        if (lane == 0) red[wav][k] = v;
    }
    __syncthreads();
    if ((int)threadIdx.x < NA) {
        const int   k = (int)threadIdx.x;
        const float v = red[0][k] + red[1][k] + red[2][k] + red[3][k];
        atomicAdd(&out[c_tab.map[k]], v * c_tab.scl[k]);
    }
}

extern "C" void kernel_launch(void* const* d_in, const int* in_sizes, int n_in,
                              void* d_out, int out_size, void* d_ws, size_t ws_size,
                              hipStream_t stream) {
    const float* pos = (const float*)d_in[0];
    float* out       = (float*)d_out;
    const int n      = in_sizes[0] / 3;  // (N,3) flat -> N points

    // d_out is poisoned before every launch; we accumulate via atomics.
    hipMemsetAsync(d_out, 0, (size_t)out_size * sizeof(float), stream);

    const int threads = 256;
    // 512 blocks = 2 blocks/CU = exactly the 2 waves/SIMD the ~200-VGPR
    // allocation can keep resident (R3 lesson: never launch blocks that
    // can't be co-resident; they just buy tail imbalance).  ~15 pts/thread
    // keeps the 121-slot shuffle epilogue at ~5% of per-wave work.
    const int blocks = 512;
    sht_kernel<<<blocks, threads, 0, stream>>>(pos, out, n, blocks);
}

// Round 6
// 119.382 us; speedup vs baseline: 1.0616x; 1.0616x over previous
//
#include <hip/hip_runtime.h>

namespace {

constexpr int LMAX = 10;
constexpr double PI_D = 3.14159265358979323846;

constexpr double dfact(int n) {
    double r = 1.0;
    for (int i = 2; i <= n; ++i) r *= (double)i;
    return r;
}

constexpr double csqrt(double x) {
    if (x <= 0.0) return 0.0;
    double g = x > 1.0 ? x : 1.0;
    for (int i = 0; i < 100; ++i) g = 0.5 * (g + x / g);
    return g;
}

constexpr double FACT[LMAX + 1] = {1., 1., 2., 6., 24., 120., 720., 5040., 40320., 362880., 3628800.};

// ---- global moment layout in workspace ------------------------------------
// Real part is a linear functional of point-moments:
//   clm_r(l,m) = scale * sum_q c(l,m,q) * (M_{q+m,l} - N_{q,l})
//   M_{p,l} = sum_pts Re(z1^p)^2 * w0 * r^l     (66 entries, p<=l)
//   N_{q,l} = sum_pts Im(z1^q)^2 * w0 * r^l     (25 entries, q=1..l/2; q=0 -> si[0]=0)
constexpr int NM_M = 66;
constexpr int mi(int p, int l) { return l * (l + 1) / 2 + p; }
constexpr int ni_base(int l) {
    int c = 0;
    for (int ll = 0; ll < l; ++ll) c += ll / 2;
    return c;
}
constexpr int ni(int q, int l) { return NM_M + ni_base(l) + (q - 1); }  // q>=1
constexpr int NM_N  = 25;
constexpr int NMOM  = NM_M + NM_N;  // 91
constexpr int ZSLOT = NMOM;         // always-zero ws slot (q=0 N references)
constexpr int WS_FLOATS = NMOM + 1; // 92

// ---- part helpers: part = l & 1 (even / odd l) ----------------------------
constexpr int part_lmax(int part) { return part ? 9 : 10; }
constexpr int nls(int part) { return part ? 5 : 6; }
constexpr int lidx(int part, int l) { return (l - part) >> 1; }
constexpr int nM(int part) { int c = 0; for (int l = part; l <= LMAX; l += 2) c += l + 1; return c; }
constexpr int nN(int part) { int c = 0; for (int l = part; l <= LMAX; l += 2) c += l / 2; return c; }
constexpr int nMom(int part) { return nM(part) + nN(part); }          // even 51, odd 40
constexpr int nI(int part) { int c = 0; for (int l = part; l <= LMAX; l += 2) c += l; return c; }
constexpr int nAcc(int part) { return nMom(part) + nI(part); }        // even 81, odd 65

constexpr int locM(int part, int p, int l) {
    int c = 0;
    for (int ll = part; ll < l; ll += 2) c += ll + 1;
    return c + p;
}
constexpr int locN(int part, int q, int l) {
    int c = nM(part);
    for (int ll = part; ll < l; ll += 2) c += ll / 2;
    return c + (q - 1);
}
constexpr int locI(int part, int m, int l) {
    int c = nMom(part);
    for (int ll = part; ll < l; ll += 2) c += ll;
    return c + (m - 1);
}

constexpr int MAXMOM = 51;
constexpr int MAXIMG = 30;

// Horner coefficient for the collapsed imag sum: (-1)^q / ((q+m)! q! (l-m-2q)!)
constexpr float ci_coef(int l, int m, int q) {
    const double c = 1.0 / (FACT[q + m] * FACT[q] * FACT[l - m - 2 * q]);
    return (q & 1) ? (float)(-c) : (float)c;
}

struct PartTab {
    short wsmap[2][MAXMOM];  // local moment slot -> global ws index
    int   omap[2][MAXIMG];   // local imag slot -> out index
    float oscl[2][MAXIMG];   // imag output scale (incl. sqrt2*(-1)^m and T==1 fold)
};

constexpr PartTab make_pt() {
    PartTab t{};
    for (int part = 0; part < 2; ++part) {
        for (int l = part; l <= LMAX; l += 2) {
            for (int p = 0; p <= l; ++p) t.wsmap[part][locM(part, p, l)] = (short)mi(p, l);
            for (int q = 1; q <= l / 2; ++q) t.wsmap[part][locN(part, q, l)] = (short)ni(q, l);
            for (int m = 1; m <= l; ++m) {
                const int    k     = locI(part, m, l) - nMom(part);
                const double scale = csqrt(dfact(l + m) * dfact(l - m)) * csqrt((2 * l + 1) / (4.0 * PI_D));
                const double f     = csqrt(2.0) * ((m & 1) ? -1.0 : 1.0);
                const double fold  = ((l - m) <= 1) ? 1.0 / (dfact(m) * dfact(l - m)) : 1.0;
                t.omap[part][k] = l * l + l - m;
                t.oscl[part][k] = (float)(f * scale * fold);
            }
        }
    }
    return t;
}

// Combine-kernel table: per real output slot, the q-term list over moments.
struct CombTab {
    int   out[66];
    float scale[66];
    int   nt[66];
    float c[66][6];
    short mIx[66][6];
    short nIx[66][6];
};

constexpr CombTab make_comb() {
    CombTab t{};
    int k = 0;
    for (int l = 0; l <= LMAX; ++l) {
        for (int m = 0; m <= l; ++m) {
            const double scale = csqrt(dfact(l + m) * dfact(l - m)) * csqrt((2 * l + 1) / (4.0 * PI_D));
            const double f     = (m == 0) ? 1.0 : csqrt(2.0) * ((m & 1) ? -1.0 : 1.0);
            t.out[k]   = (m == 0) ? l * l + l : l * l + l + m;
            t.scale[k] = (float)(f * scale);
            const int Q = (l - m) / 2;
            t.nt[k]     = Q + 1;
            for (int q = 0; q <= Q; ++q) {
                const double c = 1.0 / (FACT[q + m] * FACT[q] * FACT[l - m - 2 * q]);
                t.c[k][q]   = (float)c;
                t.mIx[k][q] = (short)mi(q + m, l);
                t.nIx[k][q] = (short)(q >= 1 ? ni(q, l) : ZSLOT);  // si[0]=0 -> zero slot
            }
            ++k;
        }
    }
    return t;
}

__constant__ PartTab c_pt = make_pt();
__constant__ CombTab c_cb = make_comb();

}  // namespace

// Round-5 lesson: >~128 live VGPRs triggers an AGPR/remat tax (compiler held
// 128 VGPR for ~175 live floats; +300 instr/pt, VALUBusy 40%, 68 us).  So the
// 2-part chassis stays, and the cut comes from algebra: the real part needs
// only m-independent moments M_{p,l}, N_{q,l} (one fma each per point) — the
// per-(l,m) coefficient combination moves to a tiny second kernel.  The
// p-major rolling power loop consumes sr/si as generated (no tables), keeping
// live state ~120 floats/part.  Imag path unchanged (Horner in rho).
template <int PART>
__device__ __forceinline__ void sht_part(const float* __restrict__ pos, float* __restrict__ out,
                                         float* __restrict__ ws, int n, int nblk) {
    constexpr int PL  = part_lmax(PART);
    constexpr int QX  = PL / 2;  // max q for N moments (even 5, odd 4)
    constexpr int NL  = nls(PART);
    constexpr int NMO = nMom(PART);
    constexpr int NAC = nAcc(PART);

    float acc[NAC];
#pragma unroll
    for (int k = 0; k < NAC; ++k) acc[k] = 0.f;

    const int bid    = (int)(blockIdx.x >> 1);
    const int tid    = bid * 256 + (int)threadIdx.x;
    const int stride = nblk * 256;

    int   i = tid;
    float x = 0.f, y = 0.f, z0 = 0.f;
    if (i < n) {
        x  = pos[3 * i + 0];
        y  = pos[3 * i + 1];
        z0 = pos[3 * i + 2];
    }

    while (i < n) {
        // software-pipelined prefetch of the next point
        const int inext = i + stride;
        float     px = 0.f, py = 0.f, pz = 0.f;
        if (inext < n) {
            px = pos[3 * inext + 0];
            py = pos[3 * inext + 1];
            pz = pos[3 * inext + 2];
        }

        const float r2  = x * x + y * y + z0 * z0;
        const float nrm = sqrtf(r2);
        const float w0  = (nrm > 0.f) ? z0 : 0.f;  // x0 * mask

        const float ar  = -0.5f * x, ai = -0.5f * y;
        const float rho = ar * ar + ai * ai;  // |z1|^2

        // wl[k] = w0 * nrm^l for the part's l values (rolling by nrm^2)
        float wl[NL];
        {
            const float n2 = nrm * nrm;
            float       w  = (PART == 0) ? w0 : w0 * nrm;
#pragma unroll
            for (int k = 0; k < NL; ++k) {
                wl[k] = w;
                w *= n2;
            }
        }

        // p-major rolling powers of z1: consume sr_p/si_p immediately into
        // moment accumulators; only zi[] is tabled (needed by imag pass).
        float zi[PL + 1];
        float zrc = 1.f, zic = 0.f;
#pragma unroll
        for (int p = 0; p <= PL; ++p) {
            if (p) {
                const float nr = ar * zrc - ai * zic;
                zic            = ar * zic + ai * zrc;
                zrc            = nr;
            }
            zi[p] = zic;
            const float srp = zrc * zrc;
#pragma unroll
            for (int l = PART; l <= LMAX; l += 2)
                if (l >= p) acc[locM(PART, p, l)] += srp * wl[lidx(PART, l)];
            if (p >= 1 && p <= QX) {
                const float sip = zic * zic;
#pragma unroll
                for (int l = PART; l <= LMAX; l += 2)
                    if (l >= 2 * p) acc[locN(PART, p, l)] += sip * wl[lidx(PART, l)];
            }
        }

        // imag pass (unchanged from the passing R2/R4 kernels)
#pragma unroll
        for (int l = PART; l <= LMAX; l += 2) {
            const float wrl = wl[lidx(PART, l)];
#pragma unroll
            for (int m = 1; m <= l; ++m) {
                const int Q = (l - m) >> 1;
                if (Q == 0) {
                    acc[locI(PART, m, l)] += zi[m] * wrl;  // coefficient folded into oscl
                } else {
                    float tq = ci_coef(l, m, Q);
#pragma unroll
                    for (int q = Q - 1; q >= 0; --q) tq = tq * rho + ci_coef(l, m, q);
                    acc[locI(PART, m, l)] += (tq * zi[m]) * wrl;
                }
            }
        }

        i  = inext;
        x  = px;
        y  = py;
        z0 = pz;
    }

    // Wave (64-lane) shuffle reduction, then cross-wave via LDS.
    __shared__ float red[4][NAC];
    const int lane = threadIdx.x & 63;
    const int wav  = threadIdx.x >> 6;
#pragma unroll
    for (int k = 0; k < NAC; ++k) {
        float v = acc[k];
#pragma unroll
        for (int off = 32; off > 0; off >>= 1) v += __shfl_down(v, off, 64);
        if (lane == 0) red[wav][k] = v;
    }
    __syncthreads();
    if ((int)threadIdx.x < NAC) {
        const int   k = (int)threadIdx.x;
        const float v = red[0][k] + red[1][k] + red[2][k] + red[3][k];
        if (k < NMO) {
            atomicAdd(&ws[c_pt.wsmap[PART][k]], v);
        } else {
            const int j = k - NMO;
            atomicAdd(&out[c_pt.omap[PART][j]], v * c_pt.oscl[PART][j]);
        }
    }
}

__global__ __launch_bounds__(256, 2) void sht_kernel(const float* __restrict__ pos,
                                                     float* __restrict__ out,
                                                     float* __restrict__ ws, int n, int nblk) {
    // part = blockIdx & 1: stride-256 round-robin keeps one part per CU (I$).
    if (blockIdx.x & 1)
        sht_part<1>(pos, out, ws, n, nblk);
    else
        sht_part<0>(pos, out, ws, n, nblk);
}

// Tiny in-stream combine: real outputs from moments.  Runs after sht_kernel;
// writes only real slots (>= l*l+l), disjoint from the imag atomics' targets.
__global__ void sht_combine(const float* __restrict__ ws, float* __restrict__ out) {
    const int t = (int)threadIdx.x;
    if (t < 66) {
        const int nt = c_cb.nt[t];
        float     v  = 0.f;
        for (int j = 0; j < nt; ++j)
            v += c_cb.c[t][j] * (ws[c_cb.mIx[t][j]] - ws[c_cb.nIx[t][j]]);
        out[c_cb.out[t]] = c_cb.scale[t] * v;
    }
}

extern "C" void kernel_launch(void* const* d_in, const int* in_sizes, int n_in,
                              void* d_out, int out_size, void* d_ws, size_t ws_size,
                              hipStream_t stream) {
    const float* pos = (const float*)d_in[0];
    float* out       = (float*)d_out;
    float* ws        = (float*)d_ws;
    const int n      = in_sizes[0] / 3;  // (N,3) flat -> N points

    // d_out is poisoned before every launch; ws holds the moment accumulators.
    hipMemsetAsync(d_out, 0, (size_t)out_size * sizeof(float), stream);
    hipMemsetAsync(d_ws, 0, WS_FLOATS * sizeof(float), stream);

    const int threads = 256;
    // R2's proven shape: 384 blocks/part = 3 blocks/CU (R3: more waves buy
    // nothing; R5: fewer, bigger kernels pay an AGPR tax).
    const int nblk_per_part = 384;
    const int blocks        = 2 * nblk_per_part;  // 768
    sht_kernel<<<blocks, threads, 0, stream>>>(pos, out, ws, n, nblk_per_part);
    sht_combine<<<1, 128, 0, stream>>>(ws, out);
}

// Round 7
// 109.441 us; speedup vs baseline: 1.1580x; 1.0908x over previous
//
#include <hip/hip_runtime.h>

namespace {

typedef float v2f __attribute__((ext_vector_type(2)));

constexpr int LMAX  = 10;
constexpr int NPART = 4;
// Register-balanced 4-way partition: packed (2-point) accumulators cost 2
// VGPRs per slot, so parts are sized to keep live state ~<=135 VGPR:
// P0{10,3}=34 acc, P1{9,4,2}=40, P2{8,5,1}=37, P3{7,6,0}=35.
constexpr int PART_OF_L[LMAX + 1] = {3, 2, 1, 0, 1, 2, 3, 3, 2, 1, 0};
constexpr double PI_D = 3.14159265358979323846;

constexpr double dfact(int n) {
    double r = 1.0;
    for (int i = 2; i <= n; ++i) r *= (double)i;
    return r;
}

constexpr double csqrt(double x) {
    if (x <= 0.0) return 0.0;
    double g = x > 1.0 ? x : 1.0;
    for (int i = 0; i < 100; ++i) g = 0.5 * (g + x / g);
    return g;
}

constexpr double FACT[LMAX + 1] = {1., 1., 2., 6., 24., 120., 720., 5040., 40320., 362880., 3628800.};

// ---- global moment layout in workspace (same as R6) -----------------------
//   clm_r(l,m) = scale * sum_q c(l,m,q) * (M_{q+m,l} - N_{q,l})
//   M_{p,l} = sum_pts Re(z1^p)^2 * w0 * r^l     (66 entries)
//   N_{q,l} = sum_pts Im(z1^q)^2 * w0 * r^l     (25 entries, q>=1)
constexpr int NM_M = 66;
constexpr int mi(int p, int l) { return l * (l + 1) / 2 + p; }
constexpr int ni_base(int l) {
    int c = 0;
    for (int ll = 0; ll < l; ++ll) c += ll / 2;
    return c;
}
constexpr int ni(int q, int l) { return NM_M + ni_base(l) + (q - 1); }
constexpr int NM_N  = 25;
constexpr int NMOM  = NM_M + NM_N;   // 91
constexpr int ZSLOT = NMOM;          // always-zero ws slot
constexpr int WS_FLOATS = NMOM + 1;  // 92

// ---- per-part helpers ------------------------------------------------------
constexpr int part_lmax(int part) {
    int mx = 0;
    for (int l = 0; l <= LMAX; ++l)
        if (PART_OF_L[l] == part) mx = l;
    return mx;
}
constexpr int nls(int part) {
    int c = 0;
    for (int l = 0; l <= LMAX; ++l)
        if (PART_OF_L[l] == part) ++c;
    return c;
}
constexpr int lidx(int part, int l) {
    int c = 0;
    for (int ll = 0; ll < l; ++ll)
        if (PART_OF_L[ll] == part) ++c;
    return c;
}
constexpr int part_ls(int part, int k) {
    int c = 0;
    for (int l = 0; l <= LMAX; ++l)
        if (PART_OF_L[l] == part) {
            if (c == k) return l;
            ++c;
        }
    return -1;
}
constexpr int nM(int part) {
    int c = 0;
    for (int l = 0; l <= LMAX; ++l)
        if (PART_OF_L[l] == part) c += l + 1;
    return c;
}
constexpr int nN(int part) {
    int c = 0;
    for (int l = 0; l <= LMAX; ++l)
        if (PART_OF_L[l] == part) c += l / 2;
    return c;
}
constexpr int nMom(int part) { return nM(part) + nN(part); }
constexpr int nI(int part) {
    int c = 0;
    for (int l = 0; l <= LMAX; ++l)
        if (PART_OF_L[l] == part) c += l;
    return c;
}
constexpr int nAcc(int part) { return nMom(part) + nI(part); }

constexpr int locM(int part, int p, int l) {
    int c = 0;
    for (int ll = 0; ll < l; ++ll)
        if (PART_OF_L[ll] == part) c += ll + 1;
    return c + p;
}
constexpr int locN(int part, int q, int l) {
    int c = nM(part);
    for (int ll = 0; ll < l; ++ll)
        if (PART_OF_L[ll] == part) c += ll / 2;
    return c + (q - 1);
}
constexpr int locI(int part, int m, int l) {
    int c = nMom(part);
    for (int ll = 0; ll < l; ++ll)
        if (PART_OF_L[ll] == part) c += ll;
    return c + (m - 1);
}

constexpr int MAXMOM = 25;  // P1: 18 M + 7 N
constexpr int MAXIMG = 15;  // P1

// Horner coefficient for the collapsed imag sum: (-1)^q / ((q+m)! q! (l-m-2q)!)
constexpr float ci_coef(int l, int m, int q) {
    const double c = 1.0 / (FACT[q + m] * FACT[q] * FACT[l - m - 2 * q]);
    return (q & 1) ? (float)(-c) : (float)c;
}

struct PartTab {
    short wsmap[NPART][MAXMOM];  // local moment slot -> global ws index
    int   omap[NPART][MAXIMG];   // local imag slot -> out index
    float oscl[NPART][MAXIMG];   // imag output scale (sqrt2*(-1)^m, T==1 fold)
};

constexpr PartTab make_pt() {
    PartTab t{};
    for (int part = 0; part < NPART; ++part) {
        for (int l = 0; l <= LMAX; ++l) {
            if (PART_OF_L[l] != part) continue;
            for (int p = 0; p <= l; ++p) t.wsmap[part][locM(part, p, l)] = (short)mi(p, l);
            for (int q = 1; q <= l / 2; ++q) t.wsmap[part][locN(part, q, l)] = (short)ni(q, l);
            for (int m = 1; m <= l; ++m) {
                const int    k     = locI(part, m, l) - nMom(part);
                const double scale = csqrt(dfact(l + m) * dfact(l - m)) * csqrt((2 * l + 1) / (4.0 * PI_D));
                const double f     = csqrt(2.0) * ((m & 1) ? -1.0 : 1.0);
                const double fold  = ((l - m) <= 1) ? 1.0 / (dfact(m) * dfact(l - m)) : 1.0;
                t.omap[part][k] = l * l + l - m;
                t.oscl[part][k] = (float)(f * scale * fold);
            }
        }
    }
    return t;
}

// Combine-kernel table: per real output slot, the q-term list over moments.
struct CombTab {
    int   out[66];
    float scale[66];
    int   nt[66];
    float c[66][6];
    short mIx[66][6];
    short nIx[66][6];
};

constexpr CombTab make_comb() {
    CombTab t{};
    int k = 0;
    for (int l = 0; l <= LMAX; ++l) {
        for (int m = 0; m <= l; ++m) {
            const double scale = csqrt(dfact(l + m) * dfact(l - m)) * csqrt((2 * l + 1) / (4.0 * PI_D));
            const double f     = (m == 0) ? 1.0 : csqrt(2.0) * ((m & 1) ? -1.0 : 1.0);
            t.out[k]   = (m == 0) ? l * l + l : l * l + l + m;
            t.scale[k] = (float)(f * scale);
            const int Q = (l - m) / 2;
            t.nt[k]     = Q + 1;
            for (int q = 0; q <= Q; ++q) {
                const double c = 1.0 / (FACT[q + m] * FACT[q] * FACT[l - m - 2 * q]);
                t.c[k][q]   = (float)c;
                t.mIx[k][q] = (short)mi(q + m, l);
                t.nIx[k][q] = (short)(q >= 1 ? ni(q, l) : ZSLOT);
            }
            ++k;
        }
    }
    return t;
}

__constant__ PartTab c_pt = make_pt();
__constant__ CombTab c_cb = make_comb();

// Load the point pair {2*ip, 2*ip+1} into packed X/Y/Z (point j in lane j).
// OOB points zero-fill; zero points contribute exactly zero (w0 = 0).
__device__ __forceinline__ void load_pair(const float* __restrict__ pos, int ip, int n,
                                          v2f& X, v2f& Y, v2f& Z) {
    const int i0 = 2 * ip;
    if (i0 + 1 < n) {
        const float2* p2 = reinterpret_cast<const float2*>(pos + 3 * i0);
        const float2  a = p2[0], b = p2[1], d = p2[2];
        X.x = a.x; X.y = b.y;
        Y.x = a.y; Y.y = d.x;
        Z.x = b.x; Z.y = d.y;
    } else if (i0 < n) {
        X.x = pos[3 * i0]; Y.x = pos[3 * i0 + 1]; Z.x = pos[3 * i0 + 2];
        X.y = 0.f; Y.y = 0.f; Z.y = 0.f;
    } else {
        X = (v2f)(0.f); Y = (v2f)(0.f); Z = (v2f)(0.f);
    }
}

}  // namespace

// R6 chassis (moment factorization for the real part, Horner-in-rho imag)
// + PACKED FP32: gfx950 has full-rate v_pk_fma_f32 / v_pk_mul_f32 — one
// instruction, 2 FP32 FLOPs.  Each thread processes TWO points as <2 x float>
// lanes, halving issued VALU instructions for the whole math body (R4's
// scalar 2-pt unroll only shared constants; this halves the encode).
// Packed accumulators cost 2 VGPR/slot -> 4 register-balanced parts keep the
// worst part at ~135 live VGPR, under the __launch_bounds__(256,3) cap of 170
// (R5 lesson: starving live state below its footprint costs a remat tax).
template <int PART>
__device__ __forceinline__ void sht_part(const float* __restrict__ pos, float* __restrict__ out,
                                         float* __restrict__ ws, int n, int nblk) {
    constexpr int PL  = part_lmax(PART);
    constexpr int QX  = PL / 2;
    constexpr int NL  = nls(PART);
    constexpr int NMO = nMom(PART);
    constexpr int NAC = nAcc(PART);

    v2f acc[NAC];
#pragma unroll
    for (int k = 0; k < NAC; ++k) acc[k] = (v2f)(0.f);

    const int bid    = (int)(blockIdx.x >> 2);
    const int tid    = bid * 256 + (int)threadIdx.x;
    const int stride = nblk * 256;  // in pairs
    const int npair  = (n + 1) >> 1;

    v2f X, Y, Z;
    int ip = tid;
    load_pair(pos, ip, n, X, Y, Z);

    while (ip < npair) {
        // software-pipelined prefetch of the next pair
        const int inext = ip + stride;
        v2f       nX, nY, nZ;
        load_pair(pos, inext, n, nX, nY, nZ);

        const v2f r2 = X * X + Y * Y + Z * Z;
        v2f       nrm;
        nrm.x = sqrtf(r2.x);
        nrm.y = sqrtf(r2.y);
        v2f w0;
        w0.x = (nrm.x > 0.f) ? Z.x : 0.f;  // x0 * mask
        w0.y = (nrm.y > 0.f) ? Z.y : 0.f;

        const v2f ar  = -0.5f * X;
        const v2f ai  = -0.5f * Y;
        const v2f rho = ar * ar + ai * ai;  // |z1|^2

        // wl[k] = w0 * nrm^l via binary decomposition (parts mix parities).
        v2f wl[NL];
        {
            const v2f p2v = nrm * nrm;
            const v2f p4v = p2v * p2v;
            const v2f p8v = p4v * p4v;
#pragma unroll
            for (int k = 0; k < NL; ++k) {
                constexpr_helper:;
                const int l = part_ls(PART, k);  // compile-time
                v2f       t = w0;
                if (l & 1) t = t * nrm;
                if (l & 2) t = t * p2v;
                if (l & 4) t = t * p4v;
                if (l & 8) t = t * p8v;
                wl[k] = t;
            }
        }

        // p-major rolling powers of z1: consume sr_p/si_p immediately into
        // moment accumulators; only zi[] is tabled (needed by imag pass).
        v2f zi[PL + 1];
        v2f zrc = (v2f)(1.f), zic = (v2f)(0.f);
#pragma unroll
        for (int p = 0; p <= PL; ++p) {
            if (p) {
                const v2f nr = ar * zrc - ai * zic;
                zic          = ar * zic + ai * zrc;
                zrc          = nr;
            }
            zi[p] = zic;
            const v2f srp = zrc * zrc;
#pragma unroll
            for (int l = 0; l <= LMAX; ++l)
                if (PART_OF_L[l] == PART && l >= p)
                    acc[locM(PART, p, l)] += srp * wl[lidx(PART, l)];
            if (p >= 1 && p <= QX) {
                const v2f sip = zic * zic;
#pragma unroll
                for (int l = 0; l <= LMAX; ++l)
                    if (PART_OF_L[l] == PART && l >= 2 * p)
                        acc[locN(PART, p, l)] += sip * wl[lidx(PART, l)];
            }
        }

        // imag pass: acc_I(l,m) += zi[m] * Horner_q(+-c * rho^q) * wrl
#pragma unroll
        for (int l = 0; l <= LMAX; ++l) {
            if (PART_OF_L[l] != PART) continue;
            const v2f wrl = wl[lidx(PART, l)];
#pragma unroll
            for (int m = 1; m <= l; ++m) {
                const int Q = (l - m) >> 1;
                if (Q == 0) {
                    acc[locI(PART, m, l)] += zi[m] * wrl;  // coeff folded into oscl
                } else {
                    v2f tq = (v2f)(ci_coef(l, m, Q));
#pragma unroll
                    for (int q = Q - 1; q >= 0; --q) tq = tq * rho + ci_coef(l, m, q);
                    acc[locI(PART, m, l)] += (tq * zi[m]) * wrl;
                }
            }
        }

        ip = inext;
        X  = nX;
        Y  = nY;
        Z  = nZ;
    }

    // Fold packed lanes, then wave shuffle reduction, then cross-wave via LDS.
    __shared__ float red[4][NAC];
    const int lane = threadIdx.x & 63;
    const int wav  = threadIdx.x >> 6;
#pragma unroll
    for (int k = 0; k < NAC; ++k) {
        float v = acc[k].x + acc[k].y;
#pragma unroll
        for (int off = 32; off > 0; off >>= 1) v += __shfl_down(v, off, 64);
        if (lane == 0) red[wav][k] = v;
    }
    __syncthreads();
    if ((int)threadIdx.x < NAC) {
        const int   k = (int)threadIdx.x;
        const float v = red[0][k] + red[1][k] + red[2][k] + red[3][k];
        if (k < NMO) {
            atomicAdd(&ws[c_pt.wsmap[PART][k]], v);
        } else {
            const int j = k - NMO;
            atomicAdd(&out[c_pt.omap[PART][j]], v * c_pt.oscl[PART][j]);
        }
    }
}

__global__ __launch_bounds__(256, 3) void sht_kernel(const float* __restrict__ pos,
                                                     float* __restrict__ out,
                                                     float* __restrict__ ws, int n, int nblk) {
    // part = blockIdx & 3: stride-256 round-robin (256 % 4 == 0) keeps all
    // resident blocks on a CU in the same part -> I$ locality.
    switch (blockIdx.x & 3) {
        case 0: sht_part<0>(pos, out, ws, n, nblk); break;
        case 1: sht_part<1>(pos, out, ws, n, nblk); break;
        case 2: sht_part<2>(pos, out, ws, n, nblk); break;
        default: sht_part<3>(pos, out, ws, n, nblk); break;
    }
}

// Tiny in-stream combine: real outputs from moments.  Writes only real slots,
// disjoint from the imag atomics' targets; stream order puts it after.
__global__ void sht_combine(const float* __restrict__ ws, float* __restrict__ out) {
    const int t = (int)threadIdx.x;
    if (t < 66) {
        const int nt = c_cb.nt[t];
        float     v  = 0.f;
        for (int j = 0; j < nt; ++j)
            v += c_cb.c[t][j] * (ws[c_cb.mIx[t][j]] - ws[c_cb.nIx[t][j]]);
        out[c_cb.out[t]] = c_cb.scale[t] * v;
    }
}

extern "C" void kernel_launch(void* const* d_in, const int* in_sizes, int n_in,
                              void* d_out, int out_size, void* d_ws, size_t ws_size,
                              hipStream_t stream) {
    const float* pos = (const float*)d_in[0];
    float* out       = (float*)d_out;
    float* ws        = (float*)d_ws;
    const int n      = in_sizes[0] / 3;  // (N,3) flat -> N points

    // d_out is poisoned before every launch; ws holds the moment accumulators.
    hipMemsetAsync(d_out, 0, (size_t)out_size * sizeof(float), stream);
    hipMemsetAsync(d_ws, 0, WS_FLOATS * sizeof(float), stream);

    const int threads = 256;
    // 192 blocks/part x 4 parts = 768 = 3 blocks/CU, matching the
    // __launch_bounds__(256,3) residency (R3: more waves buy nothing).
    // ~20 pairs/thread keeps the <=40-slot epilogue at ~3% of per-wave work.
    const int nblk_per_part = 192;
    const int blocks        = NPART * nblk_per_part;  // 768
    sht_kernel<<<blocks, threads, 0, stream>>>(pos, out, ws, n, nblk_per_part);
    sht_combine<<<1, 128, 0, stream>>>(ws, out);
}